// Round 1
// baseline (2456.752 us; speedup 1.0000x reference)
//
#include <hip/hip_runtime.h>

#define NUM_NODES 100000
#define EMB_DIM   64
#define NUM_LAYERS 3
#define NUM_EDGES 3200000
#define NUM_QUERY 1000000

// ---------------------------------------------------------------------------
// deg[dst] += 1 over all edges (grid-stride)
__global__ void deg_kernel(const int* __restrict__ dst, float* __restrict__ deg) {
    int i = blockIdx.x * blockDim.x + threadIdx.x;
    int stride = gridDim.x * blockDim.x;
    for (; i < NUM_EDGES; i += stride) {
        atomicAdd(&deg[dst[i]], 1.0f);
    }
}

// dis[n] = deg>0 ? 1/sqrt(deg) : 0   (in place)
__global__ void dis_kernel(float* __restrict__ deg_dis) {
    int i = blockIdx.x * blockDim.x + threadIdx.x;
    if (i < NUM_NODES) {
        float d = deg_dis[i];
        deg_dis[i] = (d > 0.0f) ? (1.0f / sqrtf(d)) : 0.0f;
    }
}

// out = alpha * in (vectorized float4, grid-stride over n4 float4s)
__global__ void scale_kernel(const float4* __restrict__ in, float4* __restrict__ out,
                             int n4, float alpha) {
    int i = blockIdx.x * blockDim.x + threadIdx.x;
    int stride = gridDim.x * blockDim.x;
    for (; i < n4; i += stride) {
        float4 v = in[i];
        v.x *= alpha; v.y *= alpha; v.z *= alpha; v.w *= alpha;
        out[i] = v;
    }
}

// out += alpha * in (vectorized float4, grid-stride)
__global__ void axpy_kernel(const float4* __restrict__ in, float4* __restrict__ out,
                            int n4, float alpha) {
    int i = blockIdx.x * blockDim.x + threadIdx.x;
    int stride = gridDim.x * blockDim.x;
    for (; i < n4; i += stride) {
        float4 v = in[i];
        float4 o = out[i];
        o.x += alpha * v.x; o.y += alpha * v.y; o.z += alpha * v.z; o.w += alpha * v.w;
        out[i] = o;
    }
}

// One wave (64 lanes) per edge; lane = embedding dim.
// xout[dst] += dis[src]*dis[dst] * xin[src]
__global__ void prop_kernel(const int* __restrict__ src, const int* __restrict__ dst,
                            const float* __restrict__ dis,
                            const float* __restrict__ xin, float* __restrict__ xout) {
    int wid  = (blockIdx.x * blockDim.x + threadIdx.x) >> 6;
    int lane = threadIdx.x & 63;
    if (wid >= NUM_EDGES) return;
    int s = src[wid];
    int t = dst[wid];
    float nrm = dis[s] * dis[t];
    float v = nrm * xin[(size_t)s * EMB_DIM + lane];
    atomicAdd(&xout[(size_t)t * EMB_DIM + lane], v);
}

// One wave per query: res[q] = dot(out[a], out[b]) over 64 dims
__global__ void score_kernel(const int* __restrict__ qa, const int* __restrict__ qb,
                             const float* __restrict__ x, float* __restrict__ res) {
    int wid  = (blockIdx.x * blockDim.x + threadIdx.x) >> 6;
    int lane = threadIdx.x & 63;
    if (wid >= NUM_QUERY) return;
    int a = qa[wid];
    int b = qb[wid];
    float p = x[(size_t)a * EMB_DIM + lane] * x[(size_t)b * EMB_DIM + lane];
    #pragma unroll
    for (int off = 32; off > 0; off >>= 1) p += __shfl_xor(p, off);
    if (lane == 0) res[wid] = p;
}

extern "C" void kernel_launch(void* const* d_in, const int* in_sizes, int n_in,
                              void* d_out, int out_size, void* d_ws, size_t ws_size,
                              hipStream_t stream) {
    const float* emb  = (const float*)d_in[0];
    const int*   edge = (const int*)d_in[1];   // [2][NUM_EDGES]: src then dst
    const int*   qidx = (const int*)d_in[2];   // [2][NUM_QUERY]
    float*       out  = (float*)d_out;         // [NUM_QUERY]

    const int* e_src = edge;
    const int* e_dst = edge + NUM_EDGES;
    const int* q_a   = qidx;
    const int* q_b   = qidx + NUM_QUERY;

    const size_t XBYTES = (size_t)NUM_NODES * EMB_DIM * sizeof(float); // 25.6 MB
    char* ws = (char*)d_ws;
    float* deg_dis = (float*)ws;                                  // 400 KB used
    float* xA      = (float*)(ws + (size_t)(512 * 1024));
    float* xB      = (float*)(ws + (size_t)(512 * 1024) + XBYTES);
    float* outw    = (float*)(ws + (size_t)(512 * 1024) + 2 * XBYTES);

    const float alpha = 1.0f / (NUM_LAYERS + 1);   // 0.25
    const int n4 = NUM_NODES * EMB_DIM / 4;        // 1.6M float4s

    // 1) degree + normalization
    hipMemsetAsync(deg_dis, 0, (size_t)NUM_NODES * sizeof(float), stream);
    deg_kernel<<<2048, 256, 0, stream>>>(e_dst, deg_dis);
    dis_kernel<<<(NUM_NODES + 255) / 256, 256, 0, stream>>>(deg_dis);

    // 2) out = alpha * emb
    scale_kernel<<<2048, 256, 0, stream>>>((const float4*)emb, (float4*)outw, n4, alpha);

    const int PROP_BLOCKS = (NUM_EDGES + 3) / 4;   // 4 waves (edges) per 256-thread block

    // 3) layer 1: xA = P(emb); out += alpha*xA
    hipMemsetAsync(xA, 0, XBYTES, stream);
    prop_kernel<<<PROP_BLOCKS, 256, 0, stream>>>(e_src, e_dst, deg_dis, emb, xA);
    axpy_kernel<<<2048, 256, 0, stream>>>((const float4*)xA, (float4*)outw, n4, alpha);

    // 4) layer 2: xB = P(xA); out += alpha*xB
    hipMemsetAsync(xB, 0, XBYTES, stream);
    prop_kernel<<<PROP_BLOCKS, 256, 0, stream>>>(e_src, e_dst, deg_dis, xA, xB);
    axpy_kernel<<<2048, 256, 0, stream>>>((const float4*)xB, (float4*)outw, n4, alpha);

    // 5) layer 3: xA = P(xB); out += alpha*xA
    hipMemsetAsync(xA, 0, XBYTES, stream);
    prop_kernel<<<PROP_BLOCKS, 256, 0, stream>>>(e_src, e_dst, deg_dis, xB, xA);
    axpy_kernel<<<2048, 256, 0, stream>>>((const float4*)xA, (float4*)outw, n4, alpha);

    // 6) scoring
    score_kernel<<<(NUM_QUERY + 3) / 4, 256, 0, stream>>>(q_a, q_b, outw, out);
}

// Round 2
// 1128.750 us; speedup vs baseline: 2.1765x; 2.1765x over previous
//
#include <hip/hip_runtime.h>

#define NUM_NODES 100000
#define EMB_DIM   64
#define NUM_LAYERS 3
#define NUM_EDGES 3200000
#define NUM_QUERY 1000000

// ---------------------------------------------------------------------------
// int histogram: deg[dst] += 1
__global__ void hist_kernel(const int* __restrict__ dst, int* __restrict__ deg) {
    int i = blockIdx.x * blockDim.x + threadIdx.x;
    int stride = gridDim.x * blockDim.x;
    for (; i < NUM_EDGES; i += stride) {
        atomicAdd(&deg[dst[i]], 1);
    }
}

// single-block exclusive scan: offs[0]=0, offs[i+1]=sum(deg[0..i])
__global__ void scan_kernel(const int* __restrict__ deg, int* __restrict__ offs) {
    __shared__ int tile[1024];
    __shared__ int carry;
    int t = threadIdx.x;
    if (t == 0) { carry = 0; offs[0] = 0; }
    __syncthreads();
    for (int base = 0; base < NUM_NODES; base += 1024) {
        int v = (base + t < NUM_NODES) ? deg[base + t] : 0;
        tile[t] = v;
        __syncthreads();
        // Hillis-Steele inclusive scan
        for (int d = 1; d < 1024; d <<= 1) {
            int add = (t >= d) ? tile[t - d] : 0;
            __syncthreads();
            tile[t] += add;
            __syncthreads();
        }
        int inc = tile[t] + carry;
        if (base + t < NUM_NODES) offs[base + t + 1] = inc;
        __syncthreads();               // all threads consumed old carry
        if (t == 1023) carry = inc;
        __syncthreads();               // publish new carry
    }
}

// dis[n] = deg>0 ? rsqrt(deg) : 0  — writes float over the int deg buffer's twin
__global__ void dis_kernel(const int* __restrict__ deg, float* __restrict__ dis) {
    int i = blockIdx.x * blockDim.x + threadIdx.x;
    if (i < NUM_NODES) {
        int d = deg[i];
        dis[i] = (d > 0) ? rsqrtf((float)d) : 0.0f;
    }
}

// counting-sort scatter: src_sorted grouped by dst via atomic cursor
__global__ void scatter_kernel(const int* __restrict__ src, const int* __restrict__ dst,
                               int* __restrict__ cursor, int* __restrict__ src_sorted) {
    int i = blockIdx.x * blockDim.x + threadIdx.x;
    int stride = gridDim.x * blockDim.x;
    for (; i < NUM_EDGES; i += stride) {
        int pos = atomicAdd(&cursor[dst[i]], 1);
        src_sorted[pos] = src[i];
    }
}

// One wave per node, lane = dim. Gather-side aggregation, zero atomics.
// mode 0: xout = acc; outw = alpha*(emb + acc)
// mode 1: xout = acc; outw += alpha*acc
// mode 2:             outw += alpha*acc           (xout unused)
__global__ void prop_kernel(const int* __restrict__ offs, const int* __restrict__ src_s,
                            const float* __restrict__ dis,
                            const float* __restrict__ xin, float* __restrict__ xout,
                            const float* __restrict__ emb, float* __restrict__ outw,
                            float alpha, int mode) {
    int wid  = (blockIdx.x * blockDim.x + threadIdx.x) >> 6;
    int lane = threadIdx.x & 63;
    if (wid >= NUM_NODES) return;
    int beg = offs[wid];
    int end = offs[wid + 1];
    float dt = dis[wid];
    float acc = 0.0f;
    int j = beg;
    // 4-deep edge pipeline: issue 4 independent gathers before the FMAs
    for (; j + 4 <= end; j += 4) {
        int s0 = src_s[j];
        int s1 = src_s[j + 1];
        int s2 = src_s[j + 2];
        int s3 = src_s[j + 3];
        float n0 = dis[s0] * dt;
        float n1 = dis[s1] * dt;
        float n2 = dis[s2] * dt;
        float n3 = dis[s3] * dt;
        float v0 = xin[(size_t)s0 * EMB_DIM + lane];
        float v1 = xin[(size_t)s1 * EMB_DIM + lane];
        float v2 = xin[(size_t)s2 * EMB_DIM + lane];
        float v3 = xin[(size_t)s3 * EMB_DIM + lane];
        acc = fmaf(n0, v0, acc);
        acc = fmaf(n1, v1, acc);
        acc = fmaf(n2, v2, acc);
        acc = fmaf(n3, v3, acc);
    }
    for (; j < end; ++j) {
        int s = src_s[j];
        acc = fmaf(dis[s] * dt, xin[(size_t)s * EMB_DIM + lane], acc);
    }
    size_t o = (size_t)wid * EMB_DIM + lane;
    if (mode == 0) {
        xout[o] = acc;
        outw[o] = alpha * (emb[o] + acc);
    } else if (mode == 1) {
        xout[o] = acc;
        outw[o] += alpha * acc;
    } else {
        outw[o] += alpha * acc;
    }
}

// One wave per query: res[q] = dot(out[a], out[b]) over 64 dims
__global__ void score_kernel(const int* __restrict__ qa, const int* __restrict__ qb,
                             const float* __restrict__ x, float* __restrict__ res) {
    int wid  = (blockIdx.x * blockDim.x + threadIdx.x) >> 6;
    int lane = threadIdx.x & 63;
    if (wid >= NUM_QUERY) return;
    int a = qa[wid];
    int b = qb[wid];
    float p = x[(size_t)a * EMB_DIM + lane] * x[(size_t)b * EMB_DIM + lane];
    #pragma unroll
    for (int off = 32; off > 0; off >>= 1) p += __shfl_xor(p, off);
    if (lane == 0) res[wid] = p;
}

extern "C" void kernel_launch(void* const* d_in, const int* in_sizes, int n_in,
                              void* d_out, int out_size, void* d_ws, size_t ws_size,
                              hipStream_t stream) {
    const float* emb  = (const float*)d_in[0];
    const int*   edge = (const int*)d_in[1];   // [2][NUM_EDGES]: src then dst
    const int*   qidx = (const int*)d_in[2];   // [2][NUM_QUERY]
    float*       out  = (float*)d_out;         // [NUM_QUERY]

    const int* e_src = edge;
    const int* e_dst = edge + NUM_EDGES;
    const int* q_a   = qidx;
    const int* q_b   = qidx + NUM_QUERY;

    const size_t XBYTES = (size_t)NUM_NODES * EMB_DIM * sizeof(float); // 25.6 MB
    char* ws = (char*)d_ws;
    size_t off = 0;
    auto carve = [&](size_t bytes) { void* p = ws + off; off += (bytes + 255) & ~(size_t)255; return p; };
    int*   deg_i   = (int*)  carve((size_t)NUM_NODES * 4);
    int*   offs    = (int*)  carve((size_t)(NUM_NODES + 1) * 4);
    int*   cursor  = (int*)  carve((size_t)NUM_NODES * 4);
    float* dis     = (float*)carve((size_t)NUM_NODES * 4);
    int*   src_srt = (int*)  carve((size_t)NUM_EDGES * 4);   // 12.8 MB
    float* xA      = (float*)carve(XBYTES);
    float* xB      = (float*)carve(XBYTES);
    float* outw    = (float*)carve(XBYTES);

    const float alpha = 1.0f / (NUM_LAYERS + 1);   // 0.25

    // ---- build dst-sorted CSR (once per launch; deterministic up to fp order)
    hipMemsetAsync(deg_i, 0, (size_t)NUM_NODES * 4, stream);
    hist_kernel<<<2048, 256, 0, stream>>>(e_dst, deg_i);
    scan_kernel<<<1, 1024, 0, stream>>>(deg_i, offs);
    dis_kernel<<<(NUM_NODES + 255) / 256, 256, 0, stream>>>(deg_i, dis);
    hipMemcpyAsync(cursor, offs, (size_t)NUM_NODES * 4, hipMemcpyDeviceToDevice, stream);
    scatter_kernel<<<2048, 256, 0, stream>>>(e_src, e_dst, cursor, src_srt);

    // ---- 3 propagation layers, out-accumulation fused
    const int PROP_BLOCKS = (NUM_NODES * 64 + 255) / 256;
    prop_kernel<<<PROP_BLOCKS, 256, 0, stream>>>(offs, src_srt, dis, emb, xA, emb, outw, alpha, 0);
    prop_kernel<<<PROP_BLOCKS, 256, 0, stream>>>(offs, src_srt, dis, xA,  xB, emb, outw, alpha, 1);
    prop_kernel<<<PROP_BLOCKS, 256, 0, stream>>>(offs, src_srt, dis, xB,  xA, emb, outw, alpha, 2);

    // ---- scoring
    score_kernel<<<(NUM_QUERY + 3) / 4, 256, 0, stream>>>(q_a, q_b, outw, out);
}